// Round 20
// baseline (2073.948 us; speedup 1.0000x reference)
//
#include <hip/hip_runtime.h>
#include <cmath>
#include <cstdint>

// GPT-2 (124M) forward: B=2, T=1024, C=768, H=12, L=12, V=50257, D=64
#define T_SEQ 1024
#define NH 12
#define NL 12
#define NV 50257
#define CD 768
#define M_ROWS 2048   // B*T

typedef __bf16 bf16_t;
typedef __bf16 bf16x4 __attribute__((ext_vector_type(4)));
typedef __bf16 bf16x8 __attribute__((ext_vector_type(8)));
typedef float f32x4 __attribute__((ext_vector_type(4)));

// async global->LDS, 16B per lane; LDS dest = wave-uniform base + lane*16
__device__ __forceinline__ void gload16(const bf16_t* g, bf16_t* l) {
  __builtin_amdgcn_global_load_lds(
      (const __attribute__((address_space(1))) void*)g,
      (__attribute__((address_space(3))) void*)l, 16, 0, 0);
}

// ---------------------------------------------------------------- embedding
__global__ __launch_bounds__(256) void embed_k(const int* __restrict__ idx,
    const float* __restrict__ wte, const float* __restrict__ wpe,
    float* __restrict__ x) {
  int m = blockIdx.x;
  int t = m & (T_SEQ - 1);
  int tok = idx[m];
  const float* a = wte + (size_t)tok * CD;
  const float* p = wpe + (size_t)t * CD;
  float* xr = x + (size_t)m * CD;
  int c = threadIdx.x;
  xr[c]       = a[c]       + p[c];
  xr[c + 256] = a[c + 256] + p[c + 256];
  xr[c + 512] = a[c + 512] + p[c + 512];
}

// ------------------------------------------------------- f32 -> bf16 convert
__global__ __launch_bounds__(256) void cvt_k(const float* __restrict__ in,
    bf16_t* __restrict__ out, int n4) {
  int i = blockIdx.x * 256 + threadIdx.x;
  if (i < n4) {
    float4 v = ((const float4*)in)[i];
    bf16_t* o = out + (size_t)i * 4;
    o[0] = (bf16_t)v.x; o[1] = (bf16_t)v.y;
    o[2] = (bf16_t)v.z; o[3] = (bf16_t)v.w;
  }
}

// ------------- W[K,N] f32 -> WT[N,K] bf16 (transpose), layer-batched via z
__global__ __launch_bounds__(256) void transcvt_k(const float* __restrict__ W0,
    bf16_t* __restrict__ WT0, int K, int N) {
  const float* W = W0 + (size_t)blockIdx.z * K * N;
  bf16_t* WT = WT0 + (size_t)blockIdx.z * N * K;
  __shared__ float tl[32][33];
  int k0 = blockIdx.y * 32, n0 = blockIdx.x * 32;
  int j = threadIdx.x & 31, i0 = threadIdx.x >> 5;
  #pragma unroll
  for (int i = i0; i < 32; i += 8) tl[i][j] = W[(size_t)(k0 + i) * N + n0 + j];
  __syncthreads();
  #pragma unroll
  for (int i = i0; i < 32; i += 8)
    WT[(size_t)(n0 + i) * K + k0 + j] = (bf16_t)tl[j][i];
}

// ------------------------------------------------------------- LayerNorm
// 192 threads x float4 (768 = 192*4): vectorized loads/stores (G13).
__global__ __launch_bounds__(192) void ln_k(const float* __restrict__ x,
    const float* __restrict__ w, const float* __restrict__ bi,
    bf16_t* __restrict__ out) {
  int row = blockIdx.x;
  int t = threadIdx.x;
  float4 v = ((const float4*)(x + (size_t)row * CD))[t];
  float s  = (v.x + v.y) + (v.z + v.w);
  float ss = (v.x * v.x + v.y * v.y) + (v.z * v.z + v.w * v.w);
  #pragma unroll
  for (int o = 1; o < 64; o <<= 1) { s += __shfl_xor(s, o); ss += __shfl_xor(ss, o); }
  __shared__ float sh[6];
  int wid = t >> 6, lane = t & 63;
  if (lane == 0) { sh[wid] = s; sh[3 + wid] = ss; }
  __syncthreads();
  s  = sh[0] + sh[1] + sh[2];
  ss = sh[3] + sh[4] + sh[5];
  float mean = s * (1.f / CD);
  float var  = ss * (1.f / CD) - mean * mean;
  float rs = rsqrtf(var + 1e-5f);
  float4 w4 = ((const float4*)w)[t];
  float4 b4 = ((const float4*)bi)[t];
  bf16x4 o;
  o[0] = (bf16_t)((v.x - mean) * rs * w4.x + b4.x);
  o[1] = (bf16_t)((v.y - mean) * rs * w4.y + b4.y);
  o[2] = (bf16_t)((v.z - mean) * rs * w4.z + b4.z);
  o[3] = (bf16_t)((v.w - mean) * rs * w4.w + b4.w);
  *(bf16x4*)(out + (size_t)row * CD + t * 4) = o;
}

// ------------------------------------------------------------- GEMM (B^T)
// 3 LDS buffers, 2-tile lookahead, counted vmcnt, raw s_barrier (R7-proven).
// BK=32: chunk-XOR p = c ^ ((r>>1)&3); BK=64: p = c ^ (r&7).  Both 0-confl.
// XSWZ 1: bijective XCD-chunked block swizzle (requires nwg % 8 == 0).
// EPI 0: +bias->bf16 (FUSEVT: also write V^T) | 1: gelu(+bias)->bf16 |
// 2: +bias+resid->f32 | 3: f32
template <int BM, int BN, int BK, int EPI, bool FUSEVT, int XSWZ>
__global__ __launch_bounds__(256) void gemm_bt(
    const bf16_t* __restrict__ A,     // [M,K]
    const bf16_t* __restrict__ BT,    // [N,K]
    const float* __restrict__ bias,   // [N] or null
    const float* __restrict__ resid,  // [M,N] or null
    void* __restrict__ out_p,
    bf16_t* __restrict__ vt,          // V^T out (FUSEVT) or null
    int Mdim, int Ndim, int Kdim) {
  constexpr int MR = BM / 32, NR = BN / 32;
  constexpr int KS = BK / 32;                      // k-slices per K-tile
  constexpr int LPW = (BM + BN) * BK / 2048;       // gloads per wave per tile
  __shared__ __align__(1024) bf16_t As[3][BM * BK];
  __shared__ __align__(1024) bf16_t Bs[3][BN * BK];
  const int t = threadIdx.x;
  const int wid = t >> 6, lane = t & 63;
  const int wm = wid >> 1, wn = wid & 1;
  int bx = blockIdx.x, by = blockIdx.y;
  if (XSWZ == 1) {
    int gx = gridDim.x;
    int lin = by * gx + bx;
    int cpx = (gx * gridDim.y) >> 3;
    int swz = (lin & 7) * cpx + (lin >> 3);
    bx = swz % gx; by = swz / gx;
  }
  const int m0 = by * BM, n0 = bx * BN;
  const int l15 = lane & 15, lhi = lane >> 4;

  auto stage = [&](int bi, int kt) {
    if (BK == 32) {
      const int srow = lane >> 2, schk = lane & 3;   // 16 rows x 4 chunks
      #pragma unroll
      for (int i = 0; i < BM / 64; ++i) {
        int rbase = wid * (BM / 4) + i * 16;
        int r = rbase + srow;
        int c = schk ^ ((r >> 1) & 3);
        gload16(A + (size_t)(m0 + r) * Kdim + kt + c * 8, &As[bi][rbase * 32]);
      }
      #pragma unroll
      for (int i = 0; i < BN / 64; ++i) {
        int rbase = wid * (BN / 4) + i * 16;
        int r = rbase + srow;
        int nr = n0 + r; if (nr >= Ndim) nr = Ndim - 1;
        int c = schk ^ ((r >> 1) & 3);
        gload16(BT + (size_t)nr * Kdim + kt + c * 8, &Bs[bi][rbase * 32]);
      }
    } else {  // BK == 64
      const int srow = lane >> 3, schk = lane & 7;   // 8 rows x 8 chunks
      #pragma unroll
      for (int i = 0; i < BM / 32; ++i) {
        int rbase = wid * (BM / 4) + i * 8;
        int r = rbase + srow;
        int c = schk ^ (r & 7);
        gload16(A + (size_t)(m0 + r) * Kdim + kt + c * 8, &As[bi][rbase * 64]);
      }
      #pragma unroll
      for (int i = 0; i < BN / 32; ++i) {
        int rbase = wid * (BN / 4) + i * 8;
        int r = rbase + srow;
        int nr = n0 + r; if (nr >= Ndim) nr = Ndim - 1;
        int c = schk ^ (r & 7);
        gload16(BT + (size_t)nr * Kdim + kt + c * 8, &Bs[bi][rbase * 64]);
      }
    }
  };

  f32x4 acc[MR][NR] = {};
  const int NT = Kdim / BK;

  stage(0, 0);
  if (NT > 1) stage(1, BK);
  for (int tt = 0; tt < NT; ++tt) {
    if (tt < NT - 1) asm volatile("s_waitcnt vmcnt(%0)" :: "i"(LPW) : "memory");
    else             asm volatile("s_waitcnt vmcnt(0)" ::: "memory");
    __builtin_amdgcn_sched_barrier(0);
    __builtin_amdgcn_s_barrier();       // all waves' tile-tt loads landed
    __builtin_amdgcn_sched_barrier(0);

    const bf16_t* Ab = As[tt % 3];
    const bf16_t* Bb = Bs[tt % 3];
    bf16x8 af[KS][MR], bfr[KS][NR];
    #pragma unroll
    for (int ks = 0; ks < KS; ++ks) {
      #pragma unroll
      for (int mm = 0; mm < MR; ++mm) {
        int ra = wm * (BM / 2) + mm * 16 + l15;
        int ch = (BK == 32) ? ((lhi ^ (ra >> 1)) & 3) : ((ks * 4 + lhi) ^ (ra & 7));
        af[ks][mm] = *(const bf16x8*)&Ab[ra * BK + ch * 8];
      }
      #pragma unroll
      for (int nn = 0; nn < NR; ++nn) {
        int rb = wn * (BN / 2) + nn * 16 + l15;
        int ch = (BK == 32) ? ((lhi ^ (rb >> 1)) & 3) : ((ks * 4 + lhi) ^ (rb & 7));
        bfr[ks][nn] = *(const bf16x8*)&Bb[rb * BK + ch * 8];
      }
    }
    if (tt + 2 < NT) stage((tt + 2) % 3, (tt + 2) * BK);

    __builtin_amdgcn_s_setprio(1);
    #pragma unroll
    for (int ks = 0; ks < KS; ++ks)
      #pragma unroll
      for (int mm = 0; mm < MR; ++mm)
        #pragma unroll
        for (int nn = 0; nn < NR; ++nn)
          acc[mm][nn] = __builtin_amdgcn_mfma_f32_16x16x32_bf16(
              af[ks][mm], bfr[ks][nn], acc[mm][nn], 0, 0, 0);
    __builtin_amdgcn_s_setprio(0);

    __builtin_amdgcn_sched_barrier(0);
    __builtin_amdgcn_s_barrier();       // all waves done reading buf tt
    __builtin_amdgcn_sched_barrier(0);
  }

  bf16_t* ob = (bf16_t*)out_p;
  float*  of = (float*)out_p;
  const int row0 = m0 + wm * (BM / 2);
  const int col0 = n0 + wn * (BN / 2);
  #pragma unroll
  for (int mm = 0; mm < MR; ++mm) {
    #pragma unroll
    for (int nn = 0; nn < NR; ++nn) {
      int col = col0 + nn * 16 + l15;
      if (col >= Ndim) continue;
      float bv = (EPI != 3) ? bias[col] : 0.f;
      if (EPI == 0) {
        bf16_t vv[4];
        #pragma unroll
        for (int r = 0; r < 4; ++r) {
          int row = row0 + mm * 16 + lhi * 4 + r;
          float v = acc[mm][nn][r] + bv;
          vv[r] = (bf16_t)v;
          ob[(size_t)row * Ndim + col] = vv[r];
        }
        if (FUSEVT && col >= 2 * CD) {
          // fused V^T: VT[bh][d][t], 4 consecutive t per lane (8B store)
          int h = (col - 2 * CD) >> 6;
          int d = (col - 2 * CD) & 63;
          int brow = row0 + mm * 16 + lhi * 4;
          int bh = (brow >> 10) * NH + h;
          int tt0 = brow & (T_SEQ - 1);
          *(bf16x4*)&vt[((size_t)bh * 64 + d) * T_SEQ + tt0] = *(const bf16x4*)vv;
        }
      } else {
        #pragma unroll
        for (int r = 0; r < 4; ++r) {
          int row = row0 + mm * 16 + lhi * 4 + r;
          float v = acc[mm][nn][r] + bv;
          size_t o = (size_t)row * Ndim + col;
          if (EPI == 1) {
            // gelu-tanh == v * sigmoid(2*0.79788456*(v + 0.044715 v^3))
            float u = v + 0.044715f * v * v * v;
            float w2 = 1.59576912f * u;
            v = v / (1.f + __expf(-w2));
            ob[o] = (bf16_t)v;
          } else if (EPI == 2) {
            of[o] = resid[o] + v;
          } else {
            of[o] = v;
          }
        }
      }
    }
  }
}

// ------------------ lm_head: 256^2 tile, 4 WIDE waves (128x128 wave tile),
// BK=32, 3 LDS buffers (96 KB), 2-deep lookahead, counted vmcnt(8).
// Rationale (R19 model, fits measured MfmaUtil 25.7% to within 2%): the
// 8-wave gemm_lm was LDS-read-BW-bound (96 KB/K-tile = 1129 cy vs 310 cy
// MFMA).  4 waves x 128x128 halves operand redundancy: 64 KB/K-tile.
// acc[8][8] f32x4 = 256 VGPRs -> __launch_bounds__(256,1), ~360 regs, no
// spill (m08: threshold 450).  Same 256^2 tile + XCD decode => FETCH stays
// ~128 MB (avoids R16's narrow-tile blowup).
#define LMH_GY 197
__global__ __launch_bounds__(256, 1) void gemm_lmW(
    const bf16_t* __restrict__ A,    // [2048][768]
    const bf16_t* __restrict__ BT,   // [50257][768]
    float* __restrict__ out) {
  __shared__ __align__(1024) bf16_t As[3][256 * 32];   // 48 KB
  __shared__ __align__(1024) bf16_t Bs[3][256 * 32];   // 48 KB
  const int t = threadIdx.x;
  const int wid = t >> 6, lane = t & 63;
  const int wm = wid >> 1, wn = wid & 1;               // 2M x 2N wave grid
  const int l15 = lane & 15, lhi = lane >> 4;
  const int srow = lane >> 2;        // 0..15
  const int schk = lane & 3;

  int lin = blockIdx.x;
  int swz = (lin & 7) * LMH_GY + (lin >> 3);
  const int m0 = (swz & 7) * 256;
  const int n0 = (swz >> 3) * 256;

  auto stage = [&](int bi, int kt) {
    #pragma unroll
    for (int i = 0; i < 4; ++i) {
      int rbase = wid * 64 + i * 16;
      int r = rbase + srow;
      int c = schk ^ ((r >> 1) & 3);
      gload16(A + (size_t)(m0 + r) * CD + kt * 32 + c * 8, &As[bi][rbase * 32]);
    }
    #pragma unroll
    for (int i = 0; i < 4; ++i) {
      int rbase = wid * 64 + i * 16;
      int r = rbase + srow;
      int nr = n0 + r; if (nr >= NV) nr = NV - 1;
      int c = schk ^ ((r >> 1) & 3);
      gload16(BT + (size_t)nr * CD + kt * 32 + c * 8, &Bs[bi][rbase * 32]);
    }
  };  // LPW = 8

  f32x4 acc[8][8] = {};
  const int NT = CD / 32;   // 24

  stage(0, 0); stage(1, 1);
  for (int tt = 0; tt < NT; ++tt) {
    if (tt < NT - 1) asm volatile("s_waitcnt vmcnt(8)" ::: "memory");
    else             asm volatile("s_waitcnt vmcnt(0)" ::: "memory");
    __builtin_amdgcn_sched_barrier(0);
    __builtin_amdgcn_s_barrier();       // tile tt landed for all waves
    __builtin_amdgcn_sched_barrier(0);

    const bf16_t* Ab = As[tt % 3];
    const bf16_t* Bb = Bs[tt % 3];
    bf16x8 af[8], bfr[8];
    #pragma unroll
    for (int mm = 0; mm < 8; ++mm) {
      int ra = wm * 128 + mm * 16 + l15;
      af[mm] = *(const bf16x8*)&Ab[ra * 32 + ((lhi ^ (ra >> 1)) & 3) * 8];
    }
    #pragma unroll
    for (int nn = 0; nn < 8; ++nn) {
      int rb = wn * 128 + nn * 16 + l15;
      bfr[nn] = *(const bf16x8*)&Bb[rb * 32 + ((lhi ^ (rb >> 1)) & 3) * 8];
    }
    if (tt + 2 < NT) stage((tt + 2) % 3, tt + 2);

    __builtin_amdgcn_s_setprio(1);
    #pragma unroll
    for (int mm = 0; mm < 8; ++mm)
      #pragma unroll
      for (int nn = 0; nn < 8; ++nn)
        acc[mm][nn] = __builtin_amdgcn_mfma_f32_16x16x32_bf16(af[mm], bfr[nn], acc[mm][nn], 0, 0, 0);
    __builtin_amdgcn_s_setprio(0);

    __builtin_amdgcn_sched_barrier(0);
    __builtin_amdgcn_s_barrier();       // all waves done reading buf tt
    __builtin_amdgcn_sched_barrier(0);
  }

  const int row0 = m0 + wm * 128;
  const int col0 = n0 + wn * 128;
  #pragma unroll
  for (int mm = 0; mm < 8; ++mm) {
    #pragma unroll
    for (int nn = 0; nn < 8; ++nn) {
      int col = col0 + nn * 16 + l15;
      if (col >= NV) continue;
      #pragma unroll
      for (int r = 0; r < 4; ++r)
        out[(size_t)(row0 + mm * 16 + lhi * 4 + r) * NV + col] = acc[mm][nn][r];
    }
  }
}

// ------------------------------------------------------- MFMA flash attention
// R7-proven: 1 wave/block, one 16-row q-tile per block, KVBLK=32.
__global__ __launch_bounds__(64) void attn_k(const bf16_t* __restrict__ qkv,
                                             const bf16_t* __restrict__ VT,
                                             bf16_t* __restrict__ y) {
  __shared__ __align__(16) bf16_t Ps[16 * 40];
  const int lane = threadIdx.x;
  const int gw = blockIdx.x;                 // 0 .. B*NH*64-1
  const int qi = gw & 63;
  const int bh = gw >> 6;
  const int h = bh % NH, b = bh / NH;
  const bf16_t* Qbase = qkv + (size_t)b * T_SEQ * (3 * CD) + h * 64;
  const bf16_t* Kbase = Qbase + CD;
  const bf16_t* Vt = VT + (size_t)bh * 64 * T_SEQ;

  const int l15 = lane & 15, lhi = lane >> 4;
  const int q0 = qi * 16;

  bf16x8 aq[2];
  #pragma unroll
  for (int c = 0; c < 2; ++c)
    aq[c] = *(const bf16x8*)(Qbase + (size_t)(q0 + l15) * (3 * CD) + c * 32 + lhi * 8);

  f32x4 acc[4] = {};
  float m_[4], l_[4];
  #pragma unroll
  for (int r = 0; r < 4; ++r) { m_[r] = -INFINITY; l_[r] = 0.f; }

  const int qrow = q0 + lhi * 4;
  const int nt = (q0 + 47) / 32;
  for (int kt = 0; kt < nt; ++kt) {
    const int k0 = kt * 32;
    f32x4 s[2] = {};
    #pragma unroll
    for (int c = 0; c < 2; ++c) {
      #pragma unroll
      for (int kc = 0; kc < 2; ++kc) {
        bf16x8 bk = *(const bf16x8*)(Kbase + (size_t)(k0 + kc * 16 + l15) * (3 * CD) + c * 32 + lhi * 8);
        s[kc] = __builtin_amdgcn_mfma_f32_16x16x32_bf16(aq[c], bk, s[kc], 0, 0, 0);
      }
    }
    float mx[4];
    #pragma unroll
    for (int r = 0; r < 4; ++r) mx[r] = -INFINITY;
    #pragma unroll
    for (int kc = 0; kc < 2; ++kc) {
      const int kcol = k0 + kc * 16 + l15;
      #pragma unroll
      for (int r = 0; r < 4; ++r) {
        float sv = (kcol <= qrow + r) ? s[kc][r] * 0.125f : -INFINITY;
        s[kc][r] = sv;
        mx[r] = fmaxf(mx[r], sv);
      }
    }
    #pragma unroll
    for (int r = 0; r < 4; ++r) {
      mx[r] = fmaxf(mx[r], __shfl_xor(mx[r], 1));
      mx[r] = fmaxf(mx[r], __shfl_xor(mx[r], 2));
      mx[r] = fmaxf(mx[r], __shfl_xor(mx[r], 4));
      mx[r] = fmaxf(mx[r], __shfl_xor(mx[r], 8));
    }
    float al[4], rs[4];
    #pragma unroll
    for (int r = 0; r < 4; ++r) {
      float mn = fmaxf(m_[r], mx[r]);
      al[r] = __expf(m_[r] - mn);
      m_[r] = mn;
      float p0 = __expf(s[0][r] - mn);
      float p1 = __expf(s[1][r] - mn);
      s[0][r] = p0; s[1][r] = p1;
      rs[r] = p0 + p1;
    }
    #pragma unroll
    for (int r = 0; r < 4; ++r) {
      rs[r] += __shfl_xor(rs[r], 1);
      rs[r] += __shfl_xor(rs[r], 2);
      rs[r] += __shfl_xor(rs[r], 4);
      rs[r] += __shfl_xor(rs[r], 8);
      l_[r] = l_[r] * al[r] + rs[r];
    }
    #pragma unroll
    for (int dt = 0; dt < 4; ++dt)
      #pragma unroll
      for (int r = 0; r < 4; ++r) acc[dt][r] *= al[r];
    #pragma unroll
    for (int kc = 0; kc < 2; ++kc)
      #pragma unroll
      for (int r = 0; r < 4; ++r)
        Ps[(lhi * 4 + r) * 40 + kc * 16 + l15] = (bf16_t)s[kc][r];
    bf16x8 pa = *(const bf16x8*)&Ps[l15 * 40 + lhi * 8];
    #pragma unroll
    for (int dt = 0; dt < 4; ++dt) {
      bf16x8 bv = *(const bf16x8*)(Vt + (size_t)(dt * 16 + l15) * T_SEQ + k0 + lhi * 8);
      acc[dt] = __builtin_amdgcn_mfma_f32_16x16x32_bf16(pa, bv, acc[dt], 0, 0, 0);
    }
  }
  #pragma unroll
  for (int dt = 0; dt < 4; ++dt) {
    #pragma unroll
    for (int r = 0; r < 4; ++r)
      y[(size_t)(b * T_SEQ + q0 + lhi * 4 + r) * CD + h * 64 + dt * 16 + l15] =
          (bf16_t)(acc[dt][r] / l_[r]);
  }
}

// ---------------------------------------------------------------- launcher
extern "C" void kernel_launch(void* const* d_in, const int* in_sizes, int n_in,
                              void* d_out, int out_size, void* d_ws, size_t ws_size,
                              hipStream_t stream) {
  const int*   idx   = (const int*)d_in[0];
  const float* wte   = (const float*)d_in[1];
  const float* wpe   = (const float*)d_in[2];
  const float* ln1w  = (const float*)d_in[3];
  const float* ln1b  = (const float*)d_in[4];
  const float* qkvw  = (const float*)d_in[5];
  const float* qkvb  = (const float*)d_in[6];
  const float* projw = (const float*)d_in[7];
  const float* projb = (const float*)d_in[8];
  const float* ln2w  = (const float*)d_in[9];
  const float* ln2b  = (const float*)d_in[10];
  const float* fcw   = (const float*)d_in[11];
  const float* fcb   = (const float*)d_in[12];
  const float* fcow  = (const float*)d_in[13];
  const float* fcob  = (const float*)d_in[14];
  const float* lnfw  = (const float*)d_in[15];
  const float* lnfb  = (const float*)d_in[16];
  float* out = (float*)d_out;

  char* w = (char*)d_ws;
  auto alloc = [&](size_t bytes) {
    char* p = w; w += (bytes + 255) & ~(size_t)255; return p;
  };
  float*  x     = (float*)alloc((size_t)M_ROWS * CD * 4);
  float*  x2    = (float*)alloc((size_t)M_ROWS * CD * 4);
  bf16_t* hb    = (bf16_t*)alloc((size_t)M_ROWS * CD * 2);
  bf16_t* qkvB  = (bf16_t*)alloc((size_t)M_ROWS * 3 * CD * 2);
  bf16_t* yb    = (bf16_t*)alloc((size_t)M_ROWS * CD * 2);
  bf16_t* fca   = (bf16_t*)alloc((size_t)M_ROWS * 4 * CD * 2);
  bf16_t* VT    = (bf16_t*)alloc((size_t)2 * NH * 64 * T_SEQ * 2);
  bf16_t* wteB  = (bf16_t*)alloc((size_t)NV * CD * 2);
  bf16_t* wqT_s = (bf16_t*)alloc((size_t)3 * CD * CD * 2);
  bf16_t* wpT_s = (bf16_t*)alloc((size_t)CD * CD * 2);
  bf16_t* wfT_s = (bf16_t*)alloc((size_t)4 * CD * CD * 2);
  bf16_t* woT_s = (bf16_t*)alloc((size_t)CD * 4 * CD * 2);
  const size_t qkvSz = (size_t)3 * CD * CD, prSz = (size_t)CD * CD;
  const size_t fcSz  = (size_t)4 * CD * CD, foSz = (size_t)CD * 4 * CD;
  bf16_t* wqT_b = (bf16_t*)alloc(NL * qkvSz * 2);
  bf16_t* wpT_b = (bf16_t*)alloc(NL * prSz * 2);
  bf16_t* wfT_b = (bf16_t*)alloc(NL * fcSz * 2);
  bf16_t* woT_b = (bf16_t*)alloc(NL * foSz * 2);
  const bool big = (size_t)(w - (char*)d_ws) <= ws_size;

  embed_k<<<M_ROWS, 256, 0, stream>>>(idx, wte, wpe, x);
  {
    int n4 = NV * CD / 4;
    cvt_k<<<(n4 + 255) / 256, 256, 0, stream>>>(wte, wteB, n4);
  }
  if (big) {
    transcvt_k<<<dim3(3 * CD / 32, CD / 32, NL), 256, 0, stream>>>(qkvw,  wqT_b, CD, 3 * CD);
    transcvt_k<<<dim3(CD / 32, CD / 32, NL),     256, 0, stream>>>(projw, wpT_b, CD, CD);
    transcvt_k<<<dim3(4 * CD / 32, CD / 32, NL), 256, 0, stream>>>(fcw,   wfT_b, CD, 4 * CD);
    transcvt_k<<<dim3(CD / 32, 4 * CD / 32, NL), 256, 0, stream>>>(fcow,  woT_b, 4 * CD, CD);
  }

  for (int l = 0; l < NL; ++l) {
    bf16_t *wqT, *wpT, *wfT, *woT;
    if (big) {
      wqT = wqT_b + (size_t)l * qkvSz; wpT = wpT_b + (size_t)l * prSz;
      wfT = wfT_b + (size_t)l * fcSz;  woT = woT_b + (size_t)l * foSz;
    } else {
      wqT = wqT_s; wpT = wpT_s; wfT = wfT_s; woT = woT_s;
      transcvt_k<<<dim3(3 * CD / 32, CD / 32, 1), 256, 0, stream>>>(qkvw  + (size_t)l * CD * 3 * CD, wqT, CD, 3 * CD);
      transcvt_k<<<dim3(CD / 32, CD / 32, 1),     256, 0, stream>>>(projw + (size_t)l * CD * CD,     wpT, CD, CD);
      transcvt_k<<<dim3(4 * CD / 32, CD / 32, 1), 256, 0, stream>>>(fcw   + (size_t)l * CD * 4 * CD, wfT, CD, 4 * CD);
      transcvt_k<<<dim3(CD / 32, 4 * CD / 32, 1), 256, 0, stream>>>(fcow  + (size_t)l * 4 * CD * CD, woT, 4 * CD, CD);
    }

    ln_k<<<M_ROWS, 192, 0, stream>>>(x, ln1w + l * CD, ln1b + l * CD, hb);
    gemm_bt<64, 128, 32, 0, true, 1><<<dim3(3 * CD / 128, M_ROWS / 64), 256, 0, stream>>>(
        hb, wqT, qkvb + l * 3 * CD, nullptr, qkvB, VT, M_ROWS, 3 * CD, CD);
    attn_k<<<2 * NH * 64, 64, 0, stream>>>(qkvB, VT, yb);
    gemm_bt<64, 64, 64, 2, false, 1><<<dim3(CD / 64, M_ROWS / 64), 256, 0, stream>>>(
        yb, wpT, projb + l * CD, x, x2, nullptr, M_ROWS, CD, CD);
    ln_k<<<M_ROWS, 192, 0, stream>>>(x2, ln2w + l * CD, ln2b + l * CD, hb);
    gemm_bt<64, 128, 32, 1, false, 1><<<dim3(4 * CD / 128, M_ROWS / 64), 256, 0, stream>>>(
        hb, wfT, fcb + l * 4 * CD, nullptr, fca, nullptr, M_ROWS, 4 * CD, CD);
    gemm_bt<64, 64, 64, 2, false, 1><<<dim3(CD / 64, M_ROWS / 64), 256, 0, stream>>>(
        fca, woT, fcob + l * CD, x2, x, nullptr, M_ROWS, CD, 4 * CD);
  }

  ln_k<<<M_ROWS, 192, 0, stream>>>(x, lnfw, lnfb, hb);
  gemm_lmW<<<8 * LMH_GY, 256, 0, stream>>>(hb, wteB, out);
}

// Round 21
// 2058.457 us; speedup vs baseline: 1.0075x; 1.0075x over previous
//
#include <hip/hip_runtime.h>
#include <cmath>
#include <cstdint>

// GPT-2 (124M) forward: B=2, T=1024, C=768, H=12, L=12, V=50257, D=64
#define T_SEQ 1024
#define NH 12
#define NL 12
#define NV 50257
#define CD 768
#define M_ROWS 2048   // B*T

typedef __bf16 bf16_t;
typedef __bf16 bf16x4 __attribute__((ext_vector_type(4)));
typedef __bf16 bf16x8 __attribute__((ext_vector_type(8)));
typedef float f32x4 __attribute__((ext_vector_type(4)));

// async global->LDS, 16B per lane; LDS dest = wave-uniform base + lane*16
__device__ __forceinline__ void gload16(const bf16_t* g, bf16_t* l) {
  __builtin_amdgcn_global_load_lds(
      (const __attribute__((address_space(1))) void*)g,
      (__attribute__((address_space(3))) void*)l, 16, 0, 0);
}

// ---------------------------------------------------------------- embedding
__global__ __launch_bounds__(256) void embed_k(const int* __restrict__ idx,
    const float* __restrict__ wte, const float* __restrict__ wpe,
    float* __restrict__ x) {
  int m = blockIdx.x;
  int t = m & (T_SEQ - 1);
  int tok = idx[m];
  const float* a = wte + (size_t)tok * CD;
  const float* p = wpe + (size_t)t * CD;
  float* xr = x + (size_t)m * CD;
  int c = threadIdx.x;
  xr[c]       = a[c]       + p[c];
  xr[c + 256] = a[c + 256] + p[c + 256];
  xr[c + 512] = a[c + 512] + p[c + 512];
}

// ------------------------------------------------------- f32 -> bf16 convert
__global__ __launch_bounds__(256) void cvt_k(const float* __restrict__ in,
    bf16_t* __restrict__ out, int n4) {
  int i = blockIdx.x * 256 + threadIdx.x;
  if (i < n4) {
    float4 v = ((const float4*)in)[i];
    bf16_t* o = out + (size_t)i * 4;
    o[0] = (bf16_t)v.x; o[1] = (bf16_t)v.y;
    o[2] = (bf16_t)v.z; o[3] = (bf16_t)v.w;
  }
}

// ------------- W[K,N] f32 -> WT[N,K] bf16 (transpose), layer-batched via z
__global__ __launch_bounds__(256) void transcvt_k(const float* __restrict__ W0,
    bf16_t* __restrict__ WT0, int K, int N) {
  const float* W = W0 + (size_t)blockIdx.z * K * N;
  bf16_t* WT = WT0 + (size_t)blockIdx.z * N * K;
  __shared__ float tl[32][33];
  int k0 = blockIdx.y * 32, n0 = blockIdx.x * 32;
  int j = threadIdx.x & 31, i0 = threadIdx.x >> 5;
  #pragma unroll
  for (int i = i0; i < 32; i += 8) tl[i][j] = W[(size_t)(k0 + i) * N + n0 + j];
  __syncthreads();
  #pragma unroll
  for (int i = i0; i < 32; i += 8)
    WT[(size_t)(n0 + i) * K + k0 + j] = (bf16_t)tl[j][i];
}

// ------------------------------------------------------------- LayerNorm
// 192 threads x float4 (768 = 192*4): vectorized loads/stores (G13).
__global__ __launch_bounds__(192) void ln_k(const float* __restrict__ x,
    const float* __restrict__ w, const float* __restrict__ bi,
    bf16_t* __restrict__ out) {
  int row = blockIdx.x;
  int t = threadIdx.x;
  float4 v = ((const float4*)(x + (size_t)row * CD))[t];
  float s  = (v.x + v.y) + (v.z + v.w);
  float ss = (v.x * v.x + v.y * v.y) + (v.z * v.z + v.w * v.w);
  #pragma unroll
  for (int o = 1; o < 64; o <<= 1) { s += __shfl_xor(s, o); ss += __shfl_xor(ss, o); }
  __shared__ float sh[6];
  int wid = t >> 6, lane = t & 63;
  if (lane == 0) { sh[wid] = s; sh[3 + wid] = ss; }
  __syncthreads();
  s  = sh[0] + sh[1] + sh[2];
  ss = sh[3] + sh[4] + sh[5];
  float mean = s * (1.f / CD);
  float var  = ss * (1.f / CD) - mean * mean;
  float rs = rsqrtf(var + 1e-5f);
  float4 w4 = ((const float4*)w)[t];
  float4 b4 = ((const float4*)bi)[t];
  bf16x4 o;
  o[0] = (bf16_t)((v.x - mean) * rs * w4.x + b4.x);
  o[1] = (bf16_t)((v.y - mean) * rs * w4.y + b4.y);
  o[2] = (bf16_t)((v.z - mean) * rs * w4.z + b4.z);
  o[3] = (bf16_t)((v.w - mean) * rs * w4.w + b4.w);
  *(bf16x4*)(out + (size_t)row * CD + t * 4) = o;
}

// ------------------------------------------------------------- GEMM (B^T)
// 3 LDS buffers, 2-tile lookahead, counted vmcnt, raw s_barrier (R7-proven).
// BK=32: chunk-XOR p = c ^ ((r>>1)&3); BK=64: p = c ^ (r&7).  Both 0-confl.
// XSWZ 1: bijective XCD-chunked block swizzle (requires nwg % 8 == 0).
// EPI 0: +bias->bf16 (FUSEVT: also write V^T) | 1: gelu(+bias)->bf16 |
// 2: +bias+resid->f32 | 3: f32
template <int BM, int BN, int BK, int EPI, bool FUSEVT, int XSWZ>
__global__ __launch_bounds__(256) void gemm_bt(
    const bf16_t* __restrict__ A,     // [M,K]
    const bf16_t* __restrict__ BT,    // [N,K]
    const float* __restrict__ bias,   // [N] or null
    const float* __restrict__ resid,  // [M,N] or null
    void* __restrict__ out_p,
    bf16_t* __restrict__ vt,          // V^T out (FUSEVT) or null
    int Mdim, int Ndim, int Kdim) {
  constexpr int MR = BM / 32, NR = BN / 32;
  constexpr int KS = BK / 32;                      // k-slices per K-tile
  constexpr int LPW = (BM + BN) * BK / 2048;       // gloads per wave per tile
  __shared__ __align__(1024) bf16_t As[3][BM * BK];
  __shared__ __align__(1024) bf16_t Bs[3][BN * BK];
  const int t = threadIdx.x;
  const int wid = t >> 6, lane = t & 63;
  const int wm = wid >> 1, wn = wid & 1;
  int bx = blockIdx.x, by = blockIdx.y;
  if (XSWZ == 1) {
    int gx = gridDim.x;
    int lin = by * gx + bx;
    int cpx = (gx * gridDim.y) >> 3;
    int swz = (lin & 7) * cpx + (lin >> 3);
    bx = swz % gx; by = swz / gx;
  }
  const int m0 = by * BM, n0 = bx * BN;
  const int l15 = lane & 15, lhi = lane >> 4;

  auto stage = [&](int bi, int kt) {
    if (BK == 32) {
      const int srow = lane >> 2, schk = lane & 3;   // 16 rows x 4 chunks
      #pragma unroll
      for (int i = 0; i < BM / 64; ++i) {
        int rbase = wid * (BM / 4) + i * 16;
        int r = rbase + srow;
        int c = schk ^ ((r >> 1) & 3);
        gload16(A + (size_t)(m0 + r) * Kdim + kt + c * 8, &As[bi][rbase * 32]);
      }
      #pragma unroll
      for (int i = 0; i < BN / 64; ++i) {
        int rbase = wid * (BN / 4) + i * 16;
        int r = rbase + srow;
        int nr = n0 + r; if (nr >= Ndim) nr = Ndim - 1;
        int c = schk ^ ((r >> 1) & 3);
        gload16(BT + (size_t)nr * Kdim + kt + c * 8, &Bs[bi][rbase * 32]);
      }
    } else {  // BK == 64
      const int srow = lane >> 3, schk = lane & 7;   // 8 rows x 8 chunks
      #pragma unroll
      for (int i = 0; i < BM / 32; ++i) {
        int rbase = wid * (BM / 4) + i * 8;
        int r = rbase + srow;
        int c = schk ^ (r & 7);
        gload16(A + (size_t)(m0 + r) * Kdim + kt + c * 8, &As[bi][rbase * 64]);
      }
      #pragma unroll
      for (int i = 0; i < BN / 32; ++i) {
        int rbase = wid * (BN / 4) + i * 8;
        int r = rbase + srow;
        int nr = n0 + r; if (nr >= Ndim) nr = Ndim - 1;
        int c = schk ^ (r & 7);
        gload16(BT + (size_t)nr * Kdim + kt + c * 8, &Bs[bi][rbase * 64]);
      }
    }
  };

  f32x4 acc[MR][NR] = {};
  const int NT = Kdim / BK;

  stage(0, 0);
  if (NT > 1) stage(1, BK);
  for (int tt = 0; tt < NT; ++tt) {
    if (tt < NT - 1) asm volatile("s_waitcnt vmcnt(%0)" :: "i"(LPW) : "memory");
    else             asm volatile("s_waitcnt vmcnt(0)" ::: "memory");
    __builtin_amdgcn_sched_barrier(0);
    __builtin_amdgcn_s_barrier();       // all waves' tile-tt loads landed
    __builtin_amdgcn_sched_barrier(0);

    const bf16_t* Ab = As[tt % 3];
    const bf16_t* Bb = Bs[tt % 3];
    bf16x8 af[KS][MR], bfr[KS][NR];
    #pragma unroll
    for (int ks = 0; ks < KS; ++ks) {
      #pragma unroll
      for (int mm = 0; mm < MR; ++mm) {
        int ra = wm * (BM / 2) + mm * 16 + l15;
        int ch = (BK == 32) ? ((lhi ^ (ra >> 1)) & 3) : ((ks * 4 + lhi) ^ (ra & 7));
        af[ks][mm] = *(const bf16x8*)&Ab[ra * BK + ch * 8];
      }
      #pragma unroll
      for (int nn = 0; nn < NR; ++nn) {
        int rb = wn * (BN / 2) + nn * 16 + l15;
        int ch = (BK == 32) ? ((lhi ^ (rb >> 1)) & 3) : ((ks * 4 + lhi) ^ (rb & 7));
        bfr[ks][nn] = *(const bf16x8*)&Bb[rb * BK + ch * 8];
      }
    }
    if (tt + 2 < NT) stage((tt + 2) % 3, (tt + 2) * BK);

    __builtin_amdgcn_s_setprio(1);
    #pragma unroll
    for (int ks = 0; ks < KS; ++ks)
      #pragma unroll
      for (int mm = 0; mm < MR; ++mm)
        #pragma unroll
        for (int nn = 0; nn < NR; ++nn)
          acc[mm][nn] = __builtin_amdgcn_mfma_f32_16x16x32_bf16(
              af[ks][mm], bfr[ks][nn], acc[mm][nn], 0, 0, 0);
    __builtin_amdgcn_s_setprio(0);

    __builtin_amdgcn_sched_barrier(0);
    __builtin_amdgcn_s_barrier();       // all waves done reading buf tt
    __builtin_amdgcn_sched_barrier(0);
  }

  bf16_t* ob = (bf16_t*)out_p;
  float*  of = (float*)out_p;
  const int row0 = m0 + wm * (BM / 2);
  const int col0 = n0 + wn * (BN / 2);
  #pragma unroll
  for (int mm = 0; mm < MR; ++mm) {
    #pragma unroll
    for (int nn = 0; nn < NR; ++nn) {
      int col = col0 + nn * 16 + l15;
      if (col >= Ndim) continue;
      float bv = (EPI != 3) ? bias[col] : 0.f;
      if (EPI == 0) {
        bf16_t vv[4];
        #pragma unroll
        for (int r = 0; r < 4; ++r) {
          int row = row0 + mm * 16 + lhi * 4 + r;
          float v = acc[mm][nn][r] + bv;
          vv[r] = (bf16_t)v;
          ob[(size_t)row * Ndim + col] = vv[r];
        }
        if (FUSEVT && col >= 2 * CD) {
          // fused V^T: VT[bh][d][t], 4 consecutive t per lane (8B store)
          int h = (col - 2 * CD) >> 6;
          int d = (col - 2 * CD) & 63;
          int brow = row0 + mm * 16 + lhi * 4;
          int bh = (brow >> 10) * NH + h;
          int tt0 = brow & (T_SEQ - 1);
          *(bf16x4*)&vt[((size_t)bh * 64 + d) * T_SEQ + tt0] = *(const bf16x4*)vv;
        }
      } else {
        #pragma unroll
        for (int r = 0; r < 4; ++r) {
          int row = row0 + mm * 16 + lhi * 4 + r;
          float v = acc[mm][nn][r] + bv;
          size_t o = (size_t)row * Ndim + col;
          if (EPI == 1) {
            // gelu-tanh == v * sigmoid(2*0.79788456*(v + 0.044715 v^3))
            float u = v + 0.044715f * v * v * v;
            float w2 = 1.59576912f * u;
            v = v / (1.f + __expf(-w2));
            ob[o] = (bf16_t)v;
          } else if (EPI == 2) {
            of[o] = resid[o] + v;
          } else {
            of[o] = v;
          }
        }
      }
    }
  }
}

// ---------------------- lm_head: 256^2 tile, 8 waves, BK=32, 4 LDS buffers,
// 3-deep lookahead, counted vmcnt(8).  XCD-chunked bijective swizzle.
// R10/R13/R14/R17/R19-proven: 259 us, FETCH 128 MB, MfmaUtil 25.7, 0 confl.
// Local optimum in ALL tested dimensions: narrow tiles (R12/R16), wide
// waves (R20), deeper/shallower pipelines all regress.
#define LMH_GY 197
__global__ __launch_bounds__(512, 2) void gemm_lm(
    const bf16_t* __restrict__ A,    // [2048][768]
    const bf16_t* __restrict__ BT,   // [50257][768]
    float* __restrict__ out) {
  __shared__ __align__(1024) bf16_t As[4][256 * 32];   // 64 KB
  __shared__ __align__(1024) bf16_t Bs[4][256 * 32];   // 64 KB
  const int t = threadIdx.x;
  const int wid = t >> 6, lane = t & 63;
  const int wr = wid >> 2, wc = wid & 3;               // 2M x 4N wave grid
  const int l15 = lane & 15, lhi = lane >> 4;
  const int srow = lane >> 2;        // 0..15
  const int schk = lane & 3;

  int lin = blockIdx.x;
  int swz = (lin & 7) * LMH_GY + (lin >> 3);
  const int m0 = (swz & 7) * 256;
  const int n0 = (swz >> 3) * 256;

  auto stage = [&](int bi, int kt) {
    #pragma unroll
    for (int hf = 0; hf < 2; ++hf) {
      int rb = hf * 128 + wid * 16;
      int r = rb + srow;
      int c = schk ^ ((r >> 1) & 3);
      gload16(A + (size_t)(m0 + r) * CD + kt * 32 + c * 8, &As[bi][rb * 32]);
    }
    #pragma unroll
    for (int hf = 0; hf < 2; ++hf) {
      int rb = hf * 128 + wid * 16;
      int r = rb + srow;
      int nr = n0 + r; if (nr >= NV) nr = NV - 1;
      int c = schk ^ ((r >> 1) & 3);
      gload16(BT + (size_t)nr * CD + kt * 32 + c * 8, &Bs[bi][rb * 32]);
    }
  };

  f32x4 acc[8][4] = {};
  const int NT = CD / 32;   // 24

  stage(0, 0); stage(1, 1); stage(2, 2);
  for (int tt = 0; tt < NT; ++tt) {
    if (tt < NT - 2)       asm volatile("s_waitcnt vmcnt(8)" ::: "memory");
    else if (tt == NT - 2) asm volatile("s_waitcnt vmcnt(4)" ::: "memory");
    else                   asm volatile("s_waitcnt vmcnt(0)" ::: "memory");
    __builtin_amdgcn_sched_barrier(0);
    __builtin_amdgcn_s_barrier();
    __builtin_amdgcn_sched_barrier(0);

    const bf16_t* Ab = As[tt & 3];
    const bf16_t* Bb = Bs[tt & 3];
    bf16x8 af[8], bfr[4];
    #pragma unroll
    for (int mm = 0; mm < 8; ++mm) {
      int ra = wr * 128 + mm * 16 + l15;
      af[mm] = *(const bf16x8*)&Ab[ra * 32 + ((lhi ^ (ra >> 1)) & 3) * 8];
    }
    #pragma unroll
    for (int nn = 0; nn < 4; ++nn) {
      int rb = wc * 64 + nn * 16 + l15;
      bfr[nn] = *(const bf16x8*)&Bb[rb * 32 + ((lhi ^ (rb >> 1)) & 3) * 8];
    }
    if (tt + 3 < NT) stage((tt + 3) & 3, tt + 3);

    __builtin_amdgcn_s_setprio(1);
    #pragma unroll
    for (int mm = 0; mm < 8; ++mm)
      #pragma unroll
      for (int nn = 0; nn < 4; ++nn)
        acc[mm][nn] = __builtin_amdgcn_mfma_f32_16x16x32_bf16(af[mm], bfr[nn], acc[mm][nn], 0, 0, 0);
    __builtin_amdgcn_s_setprio(0);

    __builtin_amdgcn_sched_barrier(0);
    __builtin_amdgcn_s_barrier();
    __builtin_amdgcn_sched_barrier(0);
  }

  const int row0 = m0 + wr * 128;
  const int col0 = n0 + wc * 64;
  #pragma unroll
  for (int mm = 0; mm < 8; ++mm) {
    #pragma unroll
    for (int nn = 0; nn < 4; ++nn) {
      int col = col0 + nn * 16 + l15;
      if (col >= NV) continue;
      #pragma unroll
      for (int r = 0; r < 4; ++r)
        out[(size_t)(row0 + mm * 16 + lhi * 4 + r) * NV + col] = acc[mm][nn][r];
    }
  }
}

// ------------------------------------------------------- MFMA flash attention
// R7-proven: 1 wave/block, one 16-row q-tile per block, KVBLK=32.
__global__ __launch_bounds__(64) void attn_k(const bf16_t* __restrict__ qkv,
                                             const bf16_t* __restrict__ VT,
                                             bf16_t* __restrict__ y) {
  __shared__ __align__(16) bf16_t Ps[16 * 40];
  const int lane = threadIdx.x;
  const int gw = blockIdx.x;                 // 0 .. B*NH*64-1
  const int qi = gw & 63;
  const int bh = gw >> 6;
  const int h = bh % NH, b = bh / NH;
  const bf16_t* Qbase = qkv + (size_t)b * T_SEQ * (3 * CD) + h * 64;
  const bf16_t* Kbase = Qbase + CD;
  const bf16_t* Vt = VT + (size_t)bh * 64 * T_SEQ;

  const int l15 = lane & 15, lhi = lane >> 4;
  const int q0 = qi * 16;

  bf16x8 aq[2];
  #pragma unroll
  for (int c = 0; c < 2; ++c)
    aq[c] = *(const bf16x8*)(Qbase + (size_t)(q0 + l15) * (3 * CD) + c * 32 + lhi * 8);

  f32x4 acc[4] = {};
  float m_[4], l_[4];
  #pragma unroll
  for (int r = 0; r < 4; ++r) { m_[r] = -INFINITY; l_[r] = 0.f; }

  const int qrow = q0 + lhi * 4;
  const int nt = (q0 + 47) / 32;
  for (int kt = 0; kt < nt; ++kt) {
    const int k0 = kt * 32;
    f32x4 s[2] = {};
    #pragma unroll
    for (int c = 0; c < 2; ++c) {
      #pragma unroll
      for (int kc = 0; kc < 2; ++kc) {
        bf16x8 bk = *(const bf16x8*)(Kbase + (size_t)(k0 + kc * 16 + l15) * (3 * CD) + c * 32 + lhi * 8);
        s[kc] = __builtin_amdgcn_mfma_f32_16x16x32_bf16(aq[c], bk, s[kc], 0, 0, 0);
      }
    }
    float mx[4];
    #pragma unroll
    for (int r = 0; r < 4; ++r) mx[r] = -INFINITY;
    #pragma unroll
    for (int kc = 0; kc < 2; ++kc) {
      const int kcol = k0 + kc * 16 + l15;
      #pragma unroll
      for (int r = 0; r < 4; ++r) {
        float sv = (kcol <= qrow + r) ? s[kc][r] * 0.125f : -INFINITY;
        s[kc][r] = sv;
        mx[r] = fmaxf(mx[r], sv);
      }
    }
    #pragma unroll
    for (int r = 0; r < 4; ++r) {
      mx[r] = fmaxf(mx[r], __shfl_xor(mx[r], 1));
      mx[r] = fmaxf(mx[r], __shfl_xor(mx[r], 2));
      mx[r] = fmaxf(mx[r], __shfl_xor(mx[r], 4));
      mx[r] = fmaxf(mx[r], __shfl_xor(mx[r], 8));
    }
    float al[4], rs[4];
    #pragma unroll
    for (int r = 0; r < 4; ++r) {
      float mn = fmaxf(m_[r], mx[r]);
      al[r] = __expf(m_[r] - mn);
      m_[r] = mn;
      float p0 = __expf(s[0][r] - mn);
      float p1 = __expf(s[1][r] - mn);
      s[0][r] = p0; s[1][r] = p1;
      rs[r] = p0 + p1;
    }
    #pragma unroll
    for (int r = 0; r < 4; ++r) {
      rs[r] += __shfl_xor(rs[r], 1);
      rs[r] += __shfl_xor(rs[r], 2);
      rs[r] += __shfl_xor(rs[r], 4);
      rs[r] += __shfl_xor(rs[r], 8);
      l_[r] = l_[r] * al[r] + rs[r];
    }
    #pragma unroll
    for (int dt = 0; dt < 4; ++dt)
      #pragma unroll
      for (int r = 0; r < 4; ++r) acc[dt][r] *= al[r];
    #pragma unroll
    for (int kc = 0; kc < 2; ++kc)
      #pragma unroll
      for (int r = 0; r < 4; ++r)
        Ps[(lhi * 4 + r) * 40 + kc * 16 + l15] = (bf16_t)s[kc][r];
    bf16x8 pa = *(const bf16x8*)&Ps[l15 * 40 + lhi * 8];
    #pragma unroll
    for (int dt = 0; dt < 4; ++dt) {
      bf16x8 bv = *(const bf16x8*)(Vt + (size_t)(dt * 16 + l15) * T_SEQ + k0 + lhi * 8);
      acc[dt] = __builtin_amdgcn_mfma_f32_16x16x32_bf16(pa, bv, acc[dt], 0, 0, 0);
    }
  }
  #pragma unroll
  for (int dt = 0; dt < 4; ++dt) {
    #pragma unroll
    for (int r = 0; r < 4; ++r)
      y[(size_t)(b * T_SEQ + q0 + lhi * 4 + r) * CD + h * 64 + dt * 16 + l15] =
          (bf16_t)(acc[dt][r] / l_[r]);
  }
}

// ---------------------------------------------------------------- launcher
extern "C" void kernel_launch(void* const* d_in, const int* in_sizes, int n_in,
                              void* d_out, int out_size, void* d_ws, size_t ws_size,
                              hipStream_t stream) {
  const int*   idx   = (const int*)d_in[0];
  const float* wte   = (const float*)d_in[1];
  const float* wpe   = (const float*)d_in[2];
  const float* ln1w  = (const float*)d_in[3];
  const float* ln1b  = (const float*)d_in[4];
  const float* qkvw  = (const float*)d_in[5];
  const float* qkvb  = (const float*)d_in[6];
  const float* projw = (const float*)d_in[7];
  const float* projb = (const float*)d_in[8];
  const float* ln2w  = (const float*)d_in[9];
  const float* ln2b  = (const float*)d_in[10];
  const float* fcw   = (const float*)d_in[11];
  const float* fcb   = (const float*)d_in[12];
  const float* fcow  = (const float*)d_in[13];
  const float* fcob  = (const float*)d_in[14];
  const float* lnfw  = (const float*)d_in[15];
  const float* lnfb  = (const float*)d_in[16];
  float* out = (float*)d_out;

  char* w = (char*)d_ws;
  auto alloc = [&](size_t bytes) {
    char* p = w; w += (bytes + 255) & ~(size_t)255; return p;
  };
  float*  x     = (float*)alloc((size_t)M_ROWS * CD * 4);
  float*  x2    = (float*)alloc((size_t)M_ROWS * CD * 4);
  bf16_t* hb    = (bf16_t*)alloc((size_t)M_ROWS * CD * 2);
  bf16_t* qkvB  = (bf16_t*)alloc((size_t)M_ROWS * 3 * CD * 2);
  bf16_t* yb    = (bf16_t*)alloc((size_t)M_ROWS * CD * 2);
  bf16_t* fca   = (bf16_t*)alloc((size_t)M_ROWS * 4 * CD * 2);
  bf16_t* VT    = (bf16_t*)alloc((size_t)2 * NH * 64 * T_SEQ * 2);
  bf16_t* wteB  = (bf16_t*)alloc((size_t)NV * CD * 2);
  bf16_t* wqT_s = (bf16_t*)alloc((size_t)3 * CD * CD * 2);
  bf16_t* wpT_s = (bf16_t*)alloc((size_t)CD * CD * 2);
  bf16_t* wfT_s = (bf16_t*)alloc((size_t)4 * CD * CD * 2);
  bf16_t* woT_s = (bf16_t*)alloc((size_t)CD * 4 * CD * 2);
  const size_t qkvSz = (size_t)3 * CD * CD, prSz = (size_t)CD * CD;
  const size_t fcSz  = (size_t)4 * CD * CD, foSz = (size_t)CD * 4 * CD;
  bf16_t* wqT_b = (bf16_t*)alloc(NL * qkvSz * 2);
  bf16_t* wpT_b = (bf16_t*)alloc(NL * prSz * 2);
  bf16_t* wfT_b = (bf16_t*)alloc(NL * fcSz * 2);
  bf16_t* woT_b = (bf16_t*)alloc(NL * foSz * 2);
  const bool big = (size_t)(w - (char*)d_ws) <= ws_size;

  embed_k<<<M_ROWS, 256, 0, stream>>>(idx, wte, wpe, x);
  {
    int n4 = NV * CD / 4;
    cvt_k<<<(n4 + 255) / 256, 256, 0, stream>>>(wte, wteB, n4);
  }
  if (big) {
    transcvt_k<<<dim3(3 * CD / 32, CD / 32, NL), 256, 0, stream>>>(qkvw,  wqT_b, CD, 3 * CD);
    transcvt_k<<<dim3(CD / 32, CD / 32, NL),     256, 0, stream>>>(projw, wpT_b, CD, CD);
    transcvt_k<<<dim3(4 * CD / 32, CD / 32, NL), 256, 0, stream>>>(fcw,   wfT_b, CD, 4 * CD);
    transcvt_k<<<dim3(CD / 32, 4 * CD / 32, NL), 256, 0, stream>>>(fcow,  woT_b, 4 * CD, CD);
  }

  for (int l = 0; l < NL; ++l) {
    bf16_t *wqT, *wpT, *wfT, *woT;
    if (big) {
      wqT = wqT_b + (size_t)l * qkvSz; wpT = wpT_b + (size_t)l * prSz;
      wfT = wfT_b + (size_t)l * fcSz;  woT = woT_b + (size_t)l * foSz;
    } else {
      wqT = wqT_s; wpT = wpT_s; wfT = wfT_s; woT = woT_s;
      transcvt_k<<<dim3(3 * CD / 32, CD / 32, 1), 256, 0, stream>>>(qkvw  + (size_t)l * CD * 3 * CD, wqT, CD, 3 * CD);
      transcvt_k<<<dim3(CD / 32, CD / 32, 1),     256, 0, stream>>>(projw + (size_t)l * CD * CD,     wpT, CD, CD);
      transcvt_k<<<dim3(4 * CD / 32, CD / 32, 1), 256, 0, stream>>>(fcw   + (size_t)l * CD * 4 * CD, wfT, CD, 4 * CD);
      transcvt_k<<<dim3(CD / 32, 4 * CD / 32, 1), 256, 0, stream>>>(fcow  + (size_t)l * 4 * CD * CD, woT, 4 * CD, CD);
    }

    ln_k<<<M_ROWS, 192, 0, stream>>>(x, ln1w + l * CD, ln1b + l * CD, hb);
    gemm_bt<64, 128, 32, 0, true, 1><<<dim3(3 * CD / 128, M_ROWS / 64), 256, 0, stream>>>(
        hb, wqT, qkvb + l * 3 * CD, nullptr, qkvB, VT, M_ROWS, 3 * CD, CD);
    attn_k<<<2 * NH * 64, 64, 0, stream>>>(qkvB, VT, yb);
    gemm_bt<64, 64, 64, 2, false, 1><<<dim3(CD / 64, M_ROWS / 64), 256, 0, stream>>>(
        yb, wpT, projb + l * CD, x, x2, nullptr, M_ROWS, CD, CD);
    ln_k<<<M_ROWS, 192, 0, stream>>>(x2, ln2w + l * CD, ln2b + l * CD, hb);
    gemm_bt<64, 128, 32, 1, false, 1><<<dim3(4 * CD / 128, M_ROWS / 64), 256, 0, stream>>>(
        hb, wfT, fcb + l * 4 * CD, nullptr, fca, nullptr, M_ROWS, 4 * CD, CD);
    gemm_bt<64, 64, 64, 2, false, 1><<<dim3(CD / 64, M_ROWS / 64), 256, 0, stream>>>(
        fca, woT, fcob + l * CD, x2, x, nullptr, M_ROWS, CD, 4 * CD);
  }

  ln_k<<<M_ROWS, 192, 0, stream>>>(x, lnfw, lnfb, hb);
  gemm_lm<<<8 * LMH_GY, 512, 0, stream>>>(hb, wteB, out);
}